// Round 7
// baseline (4273.398 us; speedup 1.0000x reference)
//
#include <hip/hip_runtime.h>
#include <hip/hip_bf16.h>
#include <stdint.h>

#define B4 4096
#define KZ 1088   // padded z width: 1024 + 1 (ones col) + 63 pad (34 x 32)
#define KH 160    // padded hypernet-input width: 132 + 1 + pad

typedef short bf16x8 __attribute__((ext_vector_type(8)));
typedef float f32x4 __attribute__((ext_vector_type(4)));

__device__ __forceinline__ float b2f(uint16_t u){
  union {float f; uint32_t i;} v; v.i = ((uint32_t)u)<<16; return v.f;
}
__device__ __forceinline__ uint16_t f2b(float f){
  union {float fv; uint32_t i;} v; v.fv = f;
  uint32_t r = v.i + 0x7FFFu + ((v.i>>16)&1u);
  return (uint16_t)(r>>16);
}
__device__ __forceinline__ void gload16(const void* g, void* l){
  __builtin_amdgcn_global_load_lds(
      (__attribute__((address_space(1))) void*)(g),
      (__attribute__((address_space(3))) void*)(l), 16, 0, 0);
}
// NT (non-temporal / evict-first) variant for streaming weights: keeps the
// reused z slab resident in L2. aux=2 == CPol NT on gfx950.
__device__ __forceinline__ void gload16nt(const void* g, void* l){
  __builtin_amdgcn_global_load_lds(
      (__attribute__((address_space(1))) void*)(g),
      (__attribute__((address_space(3))) void*)(l), 16, 0, 2);
}

// ---------------------------------------------------------------------------
// Transpose+pack: dst[c][k] (bf16, K-contiguous) from src fp32 [Ksrc][src_ld].
// Row k==Ksrc gets bias[sc]; k>Ksrc gets 0. Column map handles din padding:
// o=c/din_dst, i=c%din_dst, valid iff i<din_src. Writes vectorized ushort4.
// ---------------------------------------------------------------------------
__global__ __launch_bounds__(256) void transpose_pack(
    const float* __restrict__ src, const float* __restrict__ bias,
    uint16_t* __restrict__ dst,
    int Ncols, int Kdst, int Ksrc, int src_ld, int din_dst, int din_src)
{
  __shared__ float tile[32][33];
  int ct = blockIdx.x, kt = blockIdx.y;
  int tid = threadIdx.x;
  int cl = tid & 31, kg = tid >> 5;
  #pragma unroll
  for (int r = 0; r < 4; ++r){
    int kl = kg*4 + r;
    int k  = kt*32 + kl;
    int c  = ct*32 + cl;
    float v = 0.f;
    if (c < Ncols){
      int o = c / din_dst, i = c - o*din_dst;
      if (i < din_src){
        int sc = o*din_src + i;
        if (k < Ksrc)       v = src[(size_t)k*src_ld + sc];
        else if (k == Ksrc) v = bias[sc];
      }
    }
    tile[kl][cl] = v;
  }
  __syncthreads();
  int c_loc = tid >> 3, kq = tid & 7;
  int c = ct*32 + c_loc;
  if (c < Ncols){
    ushort4 st;
    uint16_t* sp = (uint16_t*)&st;
    #pragma unroll
    for (int r = 0; r < 4; ++r) sp[r] = f2b(tile[kq*4 + r][c_loc]);
    *(ushort4*)&dst[(size_t)c*Kdst + kt*32 + kq*4] = st;
  }
}

// hinp[b][k] bf16: [obs | prefs | 1 | 0...], width KH
__global__ __launch_bounds__(256) void pack_hin(
    const float* __restrict__ obs, const float* __restrict__ prefs,
    uint16_t* __restrict__ hinp)
{
  int idx = blockIdx.x*256 + threadIdx.x;   // over B4*KH
  int b = idx / KH, k = idx - b*KH;
  float v;
  if (k < 128)      v = obs[b*128 + k];
  else if (k < 132) v = prefs[b*4 + (k-128)];
  else              v = (k == 132) ? 1.f : 0.f;
  hinp[idx] = f2b(v);
}

// x0T[c][b] bf16 transposed: c<128 obs, c<160 action, c<164 prefs, else 0.
__global__ __launch_bounds__(256) void pack_x0T(
    const float* __restrict__ obs, const float* __restrict__ act,
    const float* __restrict__ prefs, uint16_t* __restrict__ x0T)
{
  int idx = blockIdx.x*256 + threadIdx.x;   // over 192*B4
  int c = idx >> 12;
  int b = idx & (B4-1);
  float v = 0.f;
  if (c < 128)      v = obs[b*128 + c];
  else if (c < 160) v = act[b*32 + (c-128)];
  else if (c < 164) v = prefs[b*4 + (c-160)];
  x0T[idx] = f2b(v);
}

// set cols 1024..1087 of z1p and zp: 1.0 at 1024, zeros after
__global__ __launch_bounds__(256) void zinit(uint16_t* __restrict__ z1p,
                                             uint16_t* __restrict__ zp)
{
  int idx = blockIdx.x*256 + threadIdx.x;   // over B4*128
  int t = idx & 127;
  int row = idx >> 7;
  uint16_t* p = (t < 64) ? z1p : zp;
  int col = 1024 + (t & 63);
  p[(size_t)row*KZ + col] = ((t & 63) == 0) ? (uint16_t)0x3F80 : (uint16_t)0;
}

// ---------------------------------------------------------------------------
// Generic 128x128 MFMA GEMM (unchanged from r6).
// ---------------------------------------------------------------------------
template<int RELU, int OUTBF, int TRANS>
__global__ __launch_bounds__(256) void gemm128(
    const uint16_t* __restrict__ A, int lda,
    const uint16_t* __restrict__ BT, int ldb,
    void* __restrict__ Cv, int ldc, int K)
{
  __shared__ char smA[128*64];
  __shared__ char smB[128*64];
  int tid = threadIdx.x, w = tid >> 6, lane = tid & 63;
  int m0 = blockIdx.x*128, n0 = blockIdx.y*128;
  const uint16_t* Ab = A  + (size_t)m0*lda;
  const uint16_t* Bb = BT + (size_t)n0*ldb;
  f32x4 acc[2][8];
  #pragma unroll
  for (int mf = 0; mf < 2; ++mf)
    #pragma unroll
    for (int nf = 0; nf < 8; ++nf) acc[mf][nf] = (f32x4){0.f,0.f,0.f,0.f};
  int colg = lane & 15, hi = lane >> 4;

  for (int k0 = 0; k0 < K; k0 += 32){
    #pragma unroll
    for (int p = 0; p < 2; ++p){
      int rb = p*4 + w;
      int row = rb*16 + (lane >> 2);
      int chunk = (lane & 3) ^ ((row >> 1) & 3);
      gload16(Ab + (size_t)row*lda + k0 + chunk*8, &smA[rb*1024]);
      gload16(Bb + (size_t)row*ldb + k0 + chunk*8, &smB[rb*1024]);
    }
    __syncthreads();
    bf16x8 af[2];
    #pragma unroll
    for (int mf = 0; mf < 2; ++mf){
      int row = w*32 + mf*16 + colg;
      af[mf] = *(const bf16x8*)&smA[row*64 + ((hi ^ ((row>>1)&3)) << 4)];
    }
    #pragma unroll
    for (int nf = 0; nf < 8; ++nf){
      int row = nf*16 + colg;
      bf16x8 bfr = *(const bf16x8*)&smB[row*64 + ((hi ^ ((row>>1)&3)) << 4)];
      acc[0][nf] = __builtin_amdgcn_mfma_f32_16x16x32_bf16(af[0], bfr, acc[0][nf], 0,0,0);
      acc[1][nf] = __builtin_amdgcn_mfma_f32_16x16x32_bf16(af[1], bfr, acc[1][nf], 0,0,0);
    }
    __syncthreads();
  }
  #pragma unroll
  for (int mf = 0; mf < 2; ++mf){
    #pragma unroll
    for (int nf = 0; nf < 8; ++nf){
      int col = n0 + nf*16 + colg;
      #pragma unroll
      for (int r = 0; r < 4; ++r){
        int row = m0 + w*32 + mf*16 + hi*4 + r;
        float v = acc[mf][nf][r];
        if (RELU) v = v > 0.f ? v : 0.f;
        if (TRANS)      ((float*)Cv)[(size_t)col*ldc + row] = v;
        else if (OUTBF) ((uint16_t*)Cv)[(size_t)row*ldc + col] = f2b(v);
        else            ((float*)Cv)[(size_t)row*ldc + col] = v;
      }
    }
  }
}

// ---------------------------------------------------------------------------
// Fused hypernet layer v7: block = 256 samples x FOUR neurons (BN=4*DINP).
// 1024 threads, 16 waves 2M x 8N; wave tile 128 x DINP/2.
// Asymmetric pipeline: A triple-buffered (distance 2), B double-buffered
// (distance 1, NT-hinted stream). Per half-tile (K=32): ONE barrier +
// counted vmcnt(1). Issue order per iter h: [phase0: read; SB(h+1)x(BC);
// MFMA 0..3] [phase1: read; SA(h+2); MFMA 4..7] => at top of h the only
// unneeded outstanding op is SA(h+1) -> vmcnt(1).
// Epilogue: x-contraction, colg shuffle-reduce, cross-half LDS reduce per
// neuron, bias+scale(+relu), store outT[o][b].
// ---------------------------------------------------------------------------
template<int DINP>
__global__ __launch_bounds__(1024, 1) void hyper4n(
    const uint16_t* __restrict__ zp,     // [B4, KZ]
    const uint16_t* __restrict__ WpT,    // [128*DINP, KZ] grouped by neuron
    const uint16_t* __restrict__ xT,     // [DINP, B4]
    const float*  __restrict__ bsbT,     // [256, B4]: row o=bias, 128+o=scale
    uint16_t* __restrict__ outT,         // [128, B4]
    int relu)
{
  constexpr int NW   = DINP/2;           // wave N-cols (96 / 64)
  constexpr int NF   = DINP/32;          // B frags per wave (6 / 4)
  constexpr int BC   = DINP/64;          // SB calls per half (3 / 2)
  constexpr int BROW = 4*DINP;           // B rows per half (768 / 512)
  constexpr int BBUF = BROW*64;          // one B buffer (48K / 32K)
  constexpr int NH   = KZ/32;            // 34 half-tiles
  __shared__ char sm[3*16384 + 2*BBUF];

  int tid = threadIdx.x, w = tid >> 6, lane = tid & 63;
  int wm = w >> 3, wn = w & 7;           // 2M x 8N
  // XCD decode: 512 blocks; each XCD owns 2 m-tiles x all 32 neuron-quads
  int f = blockIdx.x;
  int xcd = f & 7;
  int j = f >> 3;               // 0..63
  int grp = j >> 1;             // 0..31
  int mt = xcd*2 + (j & 1);     // 0..15
  int m0 = mt*256;
  const uint16_t* Ag = zp  + (size_t)m0*KZ;
  const uint16_t* Bg = WpT + (size_t)grp*BROW*KZ;
  int colg = lane & 15, hi = lane >> 4;

  f32x4 acc[8][NF];
  #pragma unroll
  for (int mf = 0; mf < 8; ++mf)
    #pragma unroll
    for (int nf = 0; nf < NF; ++nf) acc[mf][nf] = (f32x4){0.f,0.f,0.f,0.f};

  // stage: 1024 threads x 16B = 16KB = 256 rows x 64B per call.
  // Linear LDS dest (wave base + lane*16); chunk pre-swizzled by (row>>1)&3.
  auto SA = [&](int h){
    int row = tid >> 2;
    int ch  = (tid & 3) ^ ((row >> 1) & 3);
    gload16(Ag + (size_t)row*KZ + h*32 + ch*8, sm + (h%3)*16384 + w*1024);
  };
  auto SB = [&](int h, int b){
    int row = b*256 + (tid >> 2);
    int ch  = (tid & 3) ^ ((row >> 1) & 3);
    gload16nt(Bg + (size_t)row*KZ + h*32 + ch*8,
              sm + 49152 + (h&1)*BBUF + b*16384 + w*1024);
  };

  // prologue (order matters for vmcnt counting): SA(0), SB(0)xBC, SA(1)
  SA(0);
  #pragma unroll
  for (int b = 0; b < BC; ++b) SB(0,b);
  SA(1);

  for (int h = 0; h < NH; ++h){
    const char* baseA = sm + (h%3)*16384;
    const char* baseB = sm + 49152 + (h&1)*BBUF;
    if (h == NH-1) asm volatile("s_waitcnt vmcnt(0)" ::: "memory");
    else           asm volatile("s_waitcnt vmcnt(1)" ::: "memory");
    __builtin_amdgcn_s_barrier();
    // ---- phase 0: B[all nf] + A[mf 0..3]; issue SB(h+1)
    bf16x8 Bf[NF];
    #pragma unroll
    for (int nf = 0; nf < NF; ++nf){
      int rc = wn*NW + nf*16 + colg;
      Bf[nf] = *(const bf16x8*)(baseB + rc*64 + ((hi ^ ((rc>>1)&3)) << 4));
    }
    bf16x8 Af[4];
    #pragma unroll
    for (int m = 0; m < 4; ++m){
      int row = wm*128 + m*16 + colg;
      Af[m] = *(const bf16x8*)(baseA + row*64 + ((hi ^ ((row>>1)&3)) << 4));
    }
    if (h + 1 < NH){
      #pragma unroll
      for (int b = 0; b < BC; ++b) SB(h+1,b);
    }
    asm volatile("s_waitcnt lgkmcnt(0)" ::: "memory");
    __builtin_amdgcn_sched_barrier(0);
    __builtin_amdgcn_s_setprio(1);
    #pragma unroll
    for (int nf = 0; nf < NF; ++nf)
      #pragma unroll
      for (int m = 0; m < 4; ++m)
        acc[m][nf] = __builtin_amdgcn_mfma_f32_16x16x32_bf16(Af[m], Bf[nf], acc[m][nf], 0,0,0);
    __builtin_amdgcn_s_setprio(0);
    // ---- phase 1: A[mf 4..7]; issue SA(h+2)
    #pragma unroll
    for (int m = 0; m < 4; ++m){
      int row = wm*128 + (4+m)*16 + colg;
      Af[m] = *(const bf16x8*)(baseA + row*64 + ((hi ^ ((row>>1)&3)) << 4));
    }
    if (h + 2 < NH) SA(h+2);
    asm volatile("s_waitcnt lgkmcnt(0)" ::: "memory");
    __builtin_amdgcn_sched_barrier(0);
    __builtin_amdgcn_s_setprio(1);
    #pragma unroll
    for (int nf = 0; nf < NF; ++nf)
      #pragma unroll
      for (int m = 0; m < 4; ++m)
        acc[4+m][nf] = __builtin_amdgcn_mfma_f32_16x16x32_bf16(Af[m], Bf[nf], acc[4+m][nf], 0,0,0);
    __builtin_amdgcn_s_setprio(0);
  }

  // ---- epilogue: contract W rows with x ----
  float pp[8][4];
  #pragma unroll
  for (int mf = 0; mf < 8; ++mf)
    #pragma unroll
    for (int r = 0; r < 4; ++r) pp[mf][r] = 0.f;

  #pragma unroll
  for (int nf = 0; nf < NF; ++nf){
    int il = (wn & 1)*NW + nf*16 + colg;   // din-local index (same x for all o)
    #pragma unroll
    for (int mf = 0; mf < 8; ++mf){
      int b0 = m0 + wm*128 + mf*16 + hi*4;
      ushort4 xv = *(const ushort4*)(xT + (size_t)il*B4 + b0);
      f32x4 a = acc[mf][nf];
      pp[mf][0] += a[0]*b2f(xv.x); pp[mf][1] += a[1]*b2f(xv.y);
      pp[mf][2] += a[2]*b2f(xv.z); pp[mf][3] += a[3]*b2f(xv.w);
    }
  }
  #pragma unroll
  for (int mf = 0; mf < 8; ++mf)
    #pragma unroll
    for (int off = 1; off < 16; off <<= 1){
      pp[mf][0] += __shfl_xor(pp[mf][0], off);
      pp[mf][1] += __shfl_xor(pp[mf][1], off);
      pp[mf][2] += __shfl_xor(pp[mf][2], off);
      pp[mf][3] += __shfl_xor(pp[mf][3], off);
    }

  // cross-half reduce per neuron (2 waves per (neuron, row-block))
  __syncthreads();
  float* red = (float*)sm;    // [4 o_local][256 rows]
  int o_loc = wn >> 1;
  if (colg == 0 && (wn & 1) == 1){
    #pragma unroll
    for (int mf = 0; mf < 8; ++mf){
      int rloc = wm*128 + mf*16 + hi*4;
      #pragma unroll
      for (int r = 0; r < 4; ++r) red[o_loc*256 + rloc + r] = pp[mf][r];
    }
  }
  __syncthreads();
  if (colg == 0 && (wn & 1) == 0){
    int o = grp*4 + o_loc;
    #pragma unroll
    for (int mf = 0; mf < 8; ++mf){
      int rloc = wm*128 + mf*16 + hi*4;
      int b0 = m0 + rloc;
      float4 bv = *(const float4*)(bsbT + (size_t)o*B4 + b0);
      float4 sv = *(const float4*)(bsbT + (size_t)(128+o)*B4 + b0);
      float bb[4] = {bv.x, bv.y, bv.z, bv.w};
      float ss[4] = {sv.x, sv.y, sv.z, sv.w};
      ushort4 st;
      uint16_t* sp = (uint16_t*)&st;
      #pragma unroll
      for (int r = 0; r < 4; ++r){
        float val = (pp[mf][r] + red[o_loc*256 + rloc + r] + bb[r]) * ss[r];
        if (relu) val = val > 0.f ? val : 0.f;
        sp[r] = f2b(val);
      }
      *(ushort4*)(outT + (size_t)o*B4 + b0) = st;
    }
  }
}

// final layer: out[b,o] = (sum_i w2[b,o*128+i]*x2[i,b] + b2[b,o]) * s2[b,o]
__global__ __launch_bounds__(256) void finalize_k(
    const float* __restrict__ w2, const uint16_t* __restrict__ x2T,
    const float* __restrict__ bs2, float* __restrict__ out)
{
  int tid = threadIdx.x;
  int o = tid & 3;
  int b = blockIdx.x*64 + (tid >> 2);
  const float* wr = w2 + (size_t)b*512 + o*128;
  float dot = 0.f;
  #pragma unroll
  for (int i = 0; i < 128; i += 4){
    float4 wv = *(const float4*)(wr + i);
    dot += wv.x * b2f(x2T[(size_t)(i+0)*B4 + b]);
    dot += wv.y * b2f(x2T[(size_t)(i+1)*B4 + b]);
    dot += wv.z * b2f(x2T[(size_t)(i+2)*B4 + b]);
    dot += wv.w * b2f(x2T[(size_t)(i+3)*B4 + b]);
  }
  float bv = bs2[(size_t)b*128 + o];
  float sv = bs2[(size_t)b*128 + 4 + o];
  out[b*4 + o] = (dot + bv) * sv;
}

// ---------------------------------------------------------------------------
extern "C" void kernel_launch(void* const* d_in, const int* in_sizes, int n_in,
                              void* d_out, int out_size, void* d_ws, size_t ws_size,
                              hipStream_t stream)
{
  const float* obs   = (const float*)d_in[0];
  const float* act   = (const float*)d_in[1];
  const float* prefs = (const float*)d_in[2];
  const float* We1 = (const float*)d_in[3];
  const float* be1 = (const float*)d_in[4];
  const float* We2 = (const float*)d_in[5];
  const float* be2 = (const float*)d_in[6];
  const float* Ww0 = (const float*)d_in[7],  *bw0 = (const float*)d_in[8];
  const float* Wb0 = (const float*)d_in[9],  *bb0 = (const float*)d_in[10];
  const float* Ws0 = (const float*)d_in[11], *bs0i = (const float*)d_in[12];
  const float* Ww1 = (const float*)d_in[13], *bw1 = (const float*)d_in[14];
  const float* Wb1 = (const float*)d_in[15], *bb1 = (const float*)d_in[16];
  const float* Ws1 = (const float*)d_in[17], *bs1i = (const float*)d_in[18];
  const float* Ww2 = (const float*)d_in[19], *bw2 = (const float*)d_in[20];
  const float* Wb2 = (const float*)d_in[21], *bb2 = (const float*)d_in[22];
  const float* Ws2 = (const float*)d_in[23], *bs2i = (const float*)d_in[24];

  char* ws = (char*)d_ws;
  size_t off = 0;
  auto alloc = [&](size_t bytes)->char*{
    char* p = ws + off; off += (bytes + 255) & ~(size_t)255; return p;
  };
  uint16_t* WpT0  = (uint16_t*)alloc((size_t)24576*KZ*2);  // 128 * 192 rows
  uint16_t* WpT1  = (uint16_t*)alloc((size_t)16384*KZ*2);
  uint16_t* WpT2  = (uint16_t*)alloc((size_t)512*KZ*2);
  uint16_t* We1T  = (uint16_t*)alloc((size_t)1024*KH*2);
  uint16_t* We2T  = (uint16_t*)alloc((size_t)1024*KZ*2);
  uint16_t* Wbs0T = (uint16_t*)alloc((size_t)256*KZ*2);    // contiguous with
  uint16_t* Wbs1T = (uint16_t*)alloc((size_t)256*KZ*2);    // Wbs0T (512 rows)
  uint16_t* Wbs2T = (uint16_t*)alloc((size_t)128*KZ*2);
  uint16_t* hinp  = (uint16_t*)alloc((size_t)B4*KH*2);
  uint16_t* z1p   = (uint16_t*)alloc((size_t)B4*KZ*2);
  uint16_t* zp    = (uint16_t*)alloc((size_t)B4*KZ*2);
  float*    bsb0  = (float*)alloc((size_t)256*B4*4);   // transposed [256][B4]
  float*    bsb1  = (float*)alloc((size_t)256*B4*4);   // contiguous with bsb0
  float*    bsb2  = (float*)alloc((size_t)B4*128*4);
  uint16_t* x0T   = (uint16_t*)alloc((size_t)192*B4*2);
  uint16_t* x1T   = (uint16_t*)alloc((size_t)128*B4*2);
  uint16_t* x2T   = (uint16_t*)alloc((size_t)128*B4*2);
  float*    w2    = (float*)alloc((size_t)B4*512*4);
  (void)ws_size; (void)in_sizes; (void)n_in; (void)out_size;

  hipMemsetAsync(Wbs2T, 0, (size_t)128*KZ*2, stream);

  dim3 blk(256);
  auto tg = [](int nc, int kd){ return dim3((nc+31)/32, kd/32); };
  transpose_pack<<<tg(24576,KZ),blk,0,stream>>>(Ww0, bw0, WpT0, 24576, KZ, 1024, 20992, 192, 164);
  transpose_pack<<<tg(16384,KZ),blk,0,stream>>>(Ww1, bw1, WpT1, 16384, KZ, 1024, 16384, 128, 128);
  transpose_pack<<<tg(512,KZ),blk,0,stream>>>(Ww2, bw2, WpT2, 512, KZ, 1024, 512, 128, 128);
  transpose_pack<<<tg(1024,KH),blk,0,stream>>>(We1, be1, We1T, 1024, KH, 132, 1024, 1024, 1024);
  transpose_pack<<<tg(1024,KZ),blk,0,stream>>>(We2, be2, We2T, 1024, KZ, 1024, 1024, 1024, 1024);
  transpose_pack<<<tg(128,KZ),blk,0,stream>>>(Wb0, bb0, Wbs0T,          128, KZ, 1024, 128, 128, 128);
  transpose_pack<<<tg(128,KZ),blk,0,stream>>>(Ws0, bs0i, Wbs0T + 128*KZ,128, KZ, 1024, 128, 128, 128);
  transpose_pack<<<tg(128,KZ),blk,0,stream>>>(Wb1, bb1, Wbs1T,          128, KZ, 1024, 128, 128, 128);
  transpose_pack<<<tg(128,KZ),blk,0,stream>>>(Ws1, bs1i, Wbs1T + 128*KZ,128, KZ, 1024, 128, 128, 128);
  transpose_pack<<<tg(4,KZ),blk,0,stream>>>(Wb2, bb2, Wbs2T,        4, KZ, 1024, 4, 4, 4);
  transpose_pack<<<tg(4,KZ),blk,0,stream>>>(Ws2, bs2i, Wbs2T + 4*KZ,4, KZ, 1024, 4, 4, 4);

  pack_hin<<<dim3(B4*KH/256),blk,0,stream>>>(obs, prefs, hinp);
  pack_x0T<<<dim3(192*B4/256),blk,0,stream>>>(obs, act, prefs, x0T);
  zinit<<<dim3(B4*128/256),blk,0,stream>>>(z1p, zp);

  // z1 = relu(hin' @ We1')   [B,1024] bf16 into z1p (stride KZ)
  gemm128<1,1,0><<<dim3(32,8),blk,0,stream>>>(hinp, KH, We1T, KH, z1p, KZ, KH);
  // z = relu(z1' @ We2')     [B,1024] bf16 into zp (stride KZ)
  gemm128<1,1,0><<<dim3(32,8),blk,0,stream>>>(z1p, KZ, We2T, KZ, zp, KZ, KZ);
  // bias/scale heads for layers 0+1 in ONE launch: fp32 TRANSPOSED [512][B4]
  gemm128<0,0,1><<<dim3(32,4),blk,0,stream>>>(zp, KZ, Wbs0T, KZ, bsb0, B4, KZ);
  gemm128<0,0,0><<<dim3(32,1),blk,0,stream>>>(zp, KZ, Wbs2T, KZ, bsb2, 128, KZ);

  // fused hyper layers 0 and 1: 512 blocks (8 xcd * 32 quads * 2 m-tiles)
  hyper4n<192><<<dim3(512),dim3(1024),0,stream>>>(zp, WpT0, x0T, bsb0, x1T, 1);
  hyper4n<128><<<dim3(512),dim3(1024),0,stream>>>(zp, WpT1, x1T, bsb1, x2T, 1);

  // layer 2: materialize small w2 then finalize
  gemm128<0,0,0><<<dim3(32,4),blk,0,stream>>>(zp, KZ, WpT2, KZ, w2, 512, KZ);
  finalize_k<<<dim3(B4/64),blk,0,stream>>>(w2, x2T, bsb2, (float*)d_out);
}

// Round 8
// 626.895 us; speedup vs baseline: 6.8168x; 6.8168x over previous
//
#include <hip/hip_runtime.h>
#include <hip/hip_bf16.h>
#include <stdint.h>

#define B4 4096
#define KZ 1088   // padded z width: 1024 + 1 (ones col) + 63 pad (34 x 32)
#define KH 160    // padded hypernet-input width: 132 + 1 + pad

typedef short bf16x8 __attribute__((ext_vector_type(8)));
typedef float f32x4 __attribute__((ext_vector_type(4)));

__device__ __forceinline__ float b2f(uint16_t u){
  union {float f; uint32_t i;} v; v.i = ((uint32_t)u)<<16; return v.f;
}
__device__ __forceinline__ uint16_t f2b(float f){
  union {float fv; uint32_t i;} v; v.fv = f;
  uint32_t r = v.i + 0x7FFFu + ((v.i>>16)&1u);
  return (uint16_t)(r>>16);
}
__device__ __forceinline__ void gload16(const void* g, void* l){
  __builtin_amdgcn_global_load_lds(
      (__attribute__((address_space(1))) void*)(g),
      (__attribute__((address_space(3))) void*)(l), 16, 0, 0);
}

// ---------------------------------------------------------------------------
// Transpose+pack: dst[c][k] (bf16, K-contiguous) from src fp32 [Ksrc][src_ld].
// Row k==Ksrc gets bias[sc]; k>Ksrc gets 0. Column map handles din padding:
// o=c/din_dst, i=c%din_dst, valid iff i<din_src. Writes vectorized ushort4.
// ---------------------------------------------------------------------------
__global__ __launch_bounds__(256) void transpose_pack(
    const float* __restrict__ src, const float* __restrict__ bias,
    uint16_t* __restrict__ dst,
    int Ncols, int Kdst, int Ksrc, int src_ld, int din_dst, int din_src)
{
  __shared__ float tile[32][33];
  int ct = blockIdx.x, kt = blockIdx.y;
  int tid = threadIdx.x;
  int cl = tid & 31, kg = tid >> 5;
  #pragma unroll
  for (int r = 0; r < 4; ++r){
    int kl = kg*4 + r;
    int k  = kt*32 + kl;
    int c  = ct*32 + cl;
    float v = 0.f;
    if (c < Ncols){
      int o = c / din_dst, i = c - o*din_dst;
      if (i < din_src){
        int sc = o*din_src + i;
        if (k < Ksrc)       v = src[(size_t)k*src_ld + sc];
        else if (k == Ksrc) v = bias[sc];
      }
    }
    tile[kl][cl] = v;
  }
  __syncthreads();
  int c_loc = tid >> 3, kq = tid & 7;
  int c = ct*32 + c_loc;
  if (c < Ncols){
    ushort4 st;
    uint16_t* sp = (uint16_t*)&st;
    #pragma unroll
    for (int r = 0; r < 4; ++r) sp[r] = f2b(tile[kq*4 + r][c_loc]);
    *(ushort4*)&dst[(size_t)c*Kdst + kt*32 + kq*4] = st;
  }
}

// hinp[b][k] bf16: [obs | prefs | 1 | 0...], width KH
__global__ __launch_bounds__(256) void pack_hin(
    const float* __restrict__ obs, const float* __restrict__ prefs,
    uint16_t* __restrict__ hinp)
{
  int idx = blockIdx.x*256 + threadIdx.x;   // over B4*KH
  int b = idx / KH, k = idx - b*KH;
  float v;
  if (k < 128)      v = obs[b*128 + k];
  else if (k < 132) v = prefs[b*4 + (k-128)];
  else              v = (k == 132) ? 1.f : 0.f;
  hinp[idx] = f2b(v);
}

// x0T[c][b] bf16 transposed: c<128 obs, c<160 action, c<164 prefs, else 0.
__global__ __launch_bounds__(256) void pack_x0T(
    const float* __restrict__ obs, const float* __restrict__ act,
    const float* __restrict__ prefs, uint16_t* __restrict__ x0T)
{
  int idx = blockIdx.x*256 + threadIdx.x;   // over 192*B4
  int c = idx >> 12;
  int b = idx & (B4-1);
  float v = 0.f;
  if (c < 128)      v = obs[b*128 + c];
  else if (c < 160) v = act[b*32 + (c-128)];
  else if (c < 164) v = prefs[b*4 + (c-160)];
  x0T[idx] = f2b(v);
}

// set cols 1024..1087 of z1p and zp: 1.0 at 1024, zeros after
__global__ __launch_bounds__(256) void zinit(uint16_t* __restrict__ z1p,
                                             uint16_t* __restrict__ zp)
{
  int idx = blockIdx.x*256 + threadIdx.x;   // over B4*128
  int t = idx & 127;
  int row = idx >> 7;
  uint16_t* p = (t < 64) ? z1p : zp;
  int col = 1024 + (t & 63);
  p[(size_t)row*KZ + col] = ((t & 63) == 0) ? (uint16_t)0x3F80 : (uint16_t)0;
}

// ---------------------------------------------------------------------------
// Generic 128x128 MFMA GEMM (unchanged).
// ---------------------------------------------------------------------------
template<int RELU, int OUTBF, int TRANS>
__global__ __launch_bounds__(256) void gemm128(
    const uint16_t* __restrict__ A, int lda,
    const uint16_t* __restrict__ BT, int ldb,
    void* __restrict__ Cv, int ldc, int K)
{
  __shared__ char smA[128*64];
  __shared__ char smB[128*64];
  int tid = threadIdx.x, w = tid >> 6, lane = tid & 63;
  int m0 = blockIdx.x*128, n0 = blockIdx.y*128;
  const uint16_t* Ab = A  + (size_t)m0*lda;
  const uint16_t* Bb = BT + (size_t)n0*ldb;
  f32x4 acc[2][8];
  #pragma unroll
  for (int mf = 0; mf < 2; ++mf)
    #pragma unroll
    for (int nf = 0; nf < 8; ++nf) acc[mf][nf] = (f32x4){0.f,0.f,0.f,0.f};
  int colg = lane & 15, hi = lane >> 4;

  for (int k0 = 0; k0 < K; k0 += 32){
    #pragma unroll
    for (int p = 0; p < 2; ++p){
      int rb = p*4 + w;
      int row = rb*16 + (lane >> 2);
      int chunk = (lane & 3) ^ ((row >> 1) & 3);
      gload16(Ab + (size_t)row*lda + k0 + chunk*8, &smA[rb*1024]);
      gload16(Bb + (size_t)row*ldb + k0 + chunk*8, &smB[rb*1024]);
    }
    __syncthreads();
    bf16x8 af[2];
    #pragma unroll
    for (int mf = 0; mf < 2; ++mf){
      int row = w*32 + mf*16 + colg;
      af[mf] = *(const bf16x8*)&smA[row*64 + ((hi ^ ((row>>1)&3)) << 4)];
    }
    #pragma unroll
    for (int nf = 0; nf < 8; ++nf){
      int row = nf*16 + colg;
      bf16x8 bfr = *(const bf16x8*)&smB[row*64 + ((hi ^ ((row>>1)&3)) << 4)];
      acc[0][nf] = __builtin_amdgcn_mfma_f32_16x16x32_bf16(af[0], bfr, acc[0][nf], 0,0,0);
      acc[1][nf] = __builtin_amdgcn_mfma_f32_16x16x32_bf16(af[1], bfr, acc[1][nf], 0,0,0);
    }
    __syncthreads();
  }
  #pragma unroll
  for (int mf = 0; mf < 2; ++mf){
    #pragma unroll
    for (int nf = 0; nf < 8; ++nf){
      int col = n0 + nf*16 + colg;
      #pragma unroll
      for (int r = 0; r < 4; ++r){
        int row = m0 + w*32 + mf*16 + hi*4 + r;
        float v = acc[mf][nf][r];
        if (RELU) v = v > 0.f ? v : 0.f;
        if (TRANS)      ((float*)Cv)[(size_t)col*ldc + row] = v;
        else if (OUTBF) ((uint16_t*)Cv)[(size_t)row*ldc + col] = f2b(v);
        else            ((float*)Cv)[(size_t)row*ldc + col] = v;
      }
    }
  }
}

// ---------------------------------------------------------------------------
// Fused hypernet layer v8 == r6's hyper2n with the VGPR cap fixed:
// __launch_bounds__(512, 1) -> 256-VGPR budget, acc[8][NF] (192 regs) stays
// in registers (r6's (512,2) capped at 128 and spilled: WRITE_SIZE 64.5MB).
// Block = 256 samples x TWO neurons. 8 waves 2M x 4N, wave tile 128 x DINP/2.
// K pipeline: 34 half-tiles of K=32, THREE LDS half-buffers, prefetch
// distance 2, ONE barrier + counted vmcnt per half (never 0 mid-loop).
// ---------------------------------------------------------------------------
template<int DINP>
__global__ __launch_bounds__(512, 1) void hyper2n(
    const uint16_t* __restrict__ zp,     // [B4, KZ]
    const uint16_t* __restrict__ WpT,    // [128*DINP, KZ] grouped by neuron
    const uint16_t* __restrict__ xT,     // [DINP, B4]
    const float*  __restrict__ bsbT,     // [256, B4]: row o=bias, 128+o=scale
    uint16_t* __restrict__ outT,         // [128, B4]
    int relu)
{
  constexpr int NF     = DINP/32;        // frags per wave per k-half (6 / 4)
  constexpr int BCALLS = DINP/64;        // B stage calls per half (3 / 2)
  constexpr int WAITN  = 2 + BCALLS;     // counted vmcnt at half boundary
  constexpr int HBUF   = 16384 + 2*DINP*64;  // A 16KB + B 2*DINP rows x 64B
  constexpr int NH     = KZ/32;          // 34 half-tiles
  __shared__ char sm[3*HBUF];

  int tid = threadIdx.x, w = tid >> 6, lane = tid & 63;
  int wm = w >> 2, wn = w & 3;           // 2M x 4N
  // XCD decode: 1024 blocks; each XCD owns 2 m-tiles x all 64 neuron-pairs
  int f = blockIdx.x;
  int xcd = f & 7;
  int j = f >> 3;               // 0..127
  int pair = j >> 1;            // 0..63
  int mt = xcd*2 + (j & 1);     // 0..15
  int m0 = mt*256;
  const uint16_t* Ag = zp  + (size_t)m0*KZ;
  const uint16_t* Bg = WpT + (size_t)pair*(2*DINP)*KZ;
  int colg = lane & 15, hi = lane >> 4;

  f32x4 acc[8][NF];
  #pragma unroll
  for (int mf = 0; mf < 8; ++mf)
    #pragma unroll
    for (int nf = 0; nf < NF; ++nf) acc[mf][nf] = (f32x4){0.f,0.f,0.f,0.f};

  // stage call: 512 threads x 16B = 8KB = 128 rows x 64B. Linear LDS dest
  // (wave-uniform base + lane*16); 16B-chunk pre-swizzled by (row>>1)&3.
  auto SA = [&](int h, int a){
    int row = a*128 + (tid >> 2);
    int ch  = (tid & 3) ^ ((row >> 1) & 3);
    gload16(Ag + (size_t)row*KZ + h*32 + ch*8,
            sm + (h%3)*HBUF + a*8192 + w*1024);
  };
  auto SB = [&](int h, int b){
    int row = b*128 + (tid >> 2);
    int ch  = (tid & 3) ^ ((row >> 1) & 3);
    gload16(Bg + (size_t)row*KZ + h*32 + ch*8,
            sm + (h%3)*HBUF + 16384 + b*8192 + w*1024);
  };

  // prologue: stage halves 0 and 1
  SA(0,0); SA(0,1);
  #pragma unroll
  for (int b = 0; b < BCALLS; ++b) SB(0,b);
  SA(1,0); SA(1,1);
  #pragma unroll
  for (int b = 0; b < BCALLS; ++b) SB(1,b);

  for (int h = 0; h < NH; ++h){
    const char* base = sm + (h%3)*HBUF;
    if (h == NH-1) asm volatile("s_waitcnt vmcnt(0)" ::: "memory");
    else           asm volatile("s_waitcnt vmcnt(%0)" :: "i"(WAITN) : "memory");
    __builtin_amdgcn_s_barrier();
    // ---- phase 0: B[all nf] + A[mf 0..3]; issue SA(h+2)
    bf16x8 Bf[NF];
    #pragma unroll
    for (int nf = 0; nf < NF; ++nf){
      int rc = wn*(DINP/2) + nf*16 + colg;
      Bf[nf] = *(const bf16x8*)(base + 16384 + rc*64 + ((hi ^ ((rc>>1)&3)) << 4));
    }
    bf16x8 Af[4];
    #pragma unroll
    for (int m = 0; m < 4; ++m){
      int row = wm*128 + m*16 + colg;
      Af[m] = *(const bf16x8*)(base + row*64 + ((hi ^ ((row>>1)&3)) << 4));
    }
    if (h + 2 < NH){ SA(h+2,0); SA(h+2,1); }
    asm volatile("s_waitcnt lgkmcnt(0)" ::: "memory");
    __builtin_amdgcn_sched_barrier(0);
    __builtin_amdgcn_s_setprio(1);
    #pragma unroll
    for (int nf = 0; nf < NF; ++nf)
      #pragma unroll
      for (int m = 0; m < 4; ++m)
        acc[m][nf] = __builtin_amdgcn_mfma_f32_16x16x32_bf16(Af[m], Bf[nf], acc[m][nf], 0,0,0);
    __builtin_amdgcn_s_setprio(0);
    // ---- phase 1: A[mf 4..7]; issue SB(h+2)
    #pragma unroll
    for (int m = 0; m < 4; ++m){
      int row = wm*128 + (4+m)*16 + colg;
      Af[m] = *(const bf16x8*)(base + row*64 + ((hi ^ ((row>>1)&3)) << 4));
    }
    if (h + 2 < NH){
      #pragma unroll
      for (int b = 0; b < BCALLS; ++b) SB(h+2,b);
    }
    asm volatile("s_waitcnt lgkmcnt(0)" ::: "memory");
    __builtin_amdgcn_sched_barrier(0);
    __builtin_amdgcn_s_setprio(1);
    #pragma unroll
    for (int nf = 0; nf < NF; ++nf)
      #pragma unroll
      for (int m = 0; m < 4; ++m)
        acc[4+m][nf] = __builtin_amdgcn_mfma_f32_16x16x32_bf16(Af[m], Bf[nf], acc[4+m][nf], 0,0,0);
    __builtin_amdgcn_s_setprio(0);
  }

  // ---- epilogue: contract W rows with x ----
  float pp[8][4];
  #pragma unroll
  for (int mf = 0; mf < 8; ++mf)
    #pragma unroll
    for (int r = 0; r < 4; ++r) pp[mf][r] = 0.f;

  #pragma unroll
  for (int nf = 0; nf < NF; ++nf){
    int il = (wn & 1)*(DINP/2) + nf*16 + colg;   // din-local index
    #pragma unroll
    for (int mf = 0; mf < 8; ++mf){
      int b0 = m0 + wm*128 + mf*16 + hi*4;
      ushort4 xv = *(const ushort4*)(xT + (size_t)il*B4 + b0);
      f32x4 a = acc[mf][nf];
      pp[mf][0] += a[0]*b2f(xv.x); pp[mf][1] += a[1]*b2f(xv.y);
      pp[mf][2] += a[2]*b2f(xv.z); pp[mf][3] += a[3]*b2f(xv.w);
    }
  }
  #pragma unroll
  for (int mf = 0; mf < 8; ++mf)
    #pragma unroll
    for (int off = 1; off < 16; off <<= 1){
      pp[mf][0] += __shfl_xor(pp[mf][0], off);
      pp[mf][1] += __shfl_xor(pp[mf][1], off);
      pp[mf][2] += __shfl_xor(pp[mf][2], off);
      pp[mf][3] += __shfl_xor(pp[mf][3], off);
    }

  // cross-wn reduce per neuron: waves (wn&1)==1 write, (wn&1)==0 finish
  __syncthreads();
  float* red = (float*)sm;    // [2 o_local][256 rows]
  if (colg == 0 && (wn & 1) == 1){
    #pragma unroll
    for (int mf = 0; mf < 8; ++mf){
      int rloc = wm*128 + mf*16 + hi*4;
      #pragma unroll
      for (int r = 0; r < 4; ++r) red[(wn>>1)*256 + rloc + r] = pp[mf][r];
    }
  }
  __syncthreads();
  if (colg == 0 && (wn & 1) == 0){
    int o = pair*2 + (wn >> 1);
    #pragma unroll
    for (int mf = 0; mf < 8; ++mf){
      int rloc = wm*128 + mf*16 + hi*4;
      int b0 = m0 + rloc;
      float4 bv = *(const float4*)(bsbT + (size_t)o*B4 + b0);
      float4 sv = *(const float4*)(bsbT + (size_t)(128+o)*B4 + b0);
      float bb[4] = {bv.x, bv.y, bv.z, bv.w};
      float ss[4] = {sv.x, sv.y, sv.z, sv.w};
      ushort4 st;
      uint16_t* sp = (uint16_t*)&st;
      #pragma unroll
      for (int r = 0; r < 4; ++r){
        float val = (pp[mf][r] + red[(wn>>1)*256 + rloc + r] + bb[r]) * ss[r];
        if (relu) val = val > 0.f ? val : 0.f;
        sp[r] = f2b(val);
      }
      *(ushort4*)(outT + (size_t)o*B4 + b0) = st;
    }
  }
}

// final layer: out[b,o] = (sum_i w2[b,o*128+i]*x2[i,b] + b2[b,o]) * s2[b,o]
__global__ __launch_bounds__(256) void finalize_k(
    const float* __restrict__ w2, const uint16_t* __restrict__ x2T,
    const float* __restrict__ bs2, float* __restrict__ out)
{
  int tid = threadIdx.x;
  int o = tid & 3;
  int b = blockIdx.x*64 + (tid >> 2);
  const float* wr = w2 + (size_t)b*512 + o*128;
  float dot = 0.f;
  #pragma unroll
  for (int i = 0; i < 128; i += 4){
    float4 wv = *(const float4*)(wr + i);
    dot += wv.x * b2f(x2T[(size_t)(i+0)*B4 + b]);
    dot += wv.y * b2f(x2T[(size_t)(i+1)*B4 + b]);
    dot += wv.z * b2f(x2T[(size_t)(i+2)*B4 + b]);
    dot += wv.w * b2f(x2T[(size_t)(i+3)*B4 + b]);
  }
  float bv = bs2[(size_t)b*128 + o];
  float sv = bs2[(size_t)b*128 + 4 + o];
  out[b*4 + o] = (dot + bv) * sv;
}

// ---------------------------------------------------------------------------
extern "C" void kernel_launch(void* const* d_in, const int* in_sizes, int n_in,
                              void* d_out, int out_size, void* d_ws, size_t ws_size,
                              hipStream_t stream)
{
  const float* obs   = (const float*)d_in[0];
  const float* act   = (const float*)d_in[1];
  const float* prefs = (const float*)d_in[2];
  const float* We1 = (const float*)d_in[3];
  const float* be1 = (const float*)d_in[4];
  const float* We2 = (const float*)d_in[5];
  const float* be2 = (const float*)d_in[6];
  const float* Ww0 = (const float*)d_in[7],  *bw0 = (const float*)d_in[8];
  const float* Wb0 = (const float*)d_in[9],  *bb0 = (const float*)d_in[10];
  const float* Ws0 = (const float*)d_in[11], *bs0i = (const float*)d_in[12];
  const float* Ww1 = (const float*)d_in[13], *bw1 = (const float*)d_in[14];
  const float* Wb1 = (const float*)d_in[15], *bb1 = (const float*)d_in[16];
  const float* Ws1 = (const float*)d_in[17], *bs1i = (const float*)d_in[18];
  const float* Ww2 = (const float*)d_in[19], *bw2 = (const float*)d_in[20];
  const float* Wb2 = (const float*)d_in[21], *bb2 = (const float*)d_in[22];
  const float* Ws2 = (const float*)d_in[23], *bs2i = (const float*)d_in[24];

  char* ws = (char*)d_ws;
  size_t off = 0;
  auto alloc = [&](size_t bytes)->char*{
    char* p = ws + off; off += (bytes + 255) & ~(size_t)255; return p;
  };
  uint16_t* WpT0  = (uint16_t*)alloc((size_t)24576*KZ*2);  // 128 * 192 rows
  uint16_t* WpT1  = (uint16_t*)alloc((size_t)16384*KZ*2);
  uint16_t* WpT2  = (uint16_t*)alloc((size_t)512*KZ*2);
  uint16_t* We1T  = (uint16_t*)alloc((size_t)1024*KH*2);
  uint16_t* We2T  = (uint16_t*)alloc((size_t)1024*KZ*2);
  uint16_t* Wbs0T = (uint16_t*)alloc((size_t)256*KZ*2);    // contiguous with
  uint16_t* Wbs1T = (uint16_t*)alloc((size_t)256*KZ*2);    // Wbs0T (512 rows)
  uint16_t* Wbs2T = (uint16_t*)alloc((size_t)128*KZ*2);
  uint16_t* hinp  = (uint16_t*)alloc((size_t)B4*KH*2);
  uint16_t* z1p   = (uint16_t*)alloc((size_t)B4*KZ*2);
  uint16_t* zp    = (uint16_t*)alloc((size_t)B4*KZ*2);
  float*    bsb0  = (float*)alloc((size_t)256*B4*4);   // transposed [256][B4]
  float*    bsb1  = (float*)alloc((size_t)256*B4*4);   // contiguous with bsb0
  float*    bsb2  = (float*)alloc((size_t)B4*128*4);
  uint16_t* x0T   = (uint16_t*)alloc((size_t)192*B4*2);
  uint16_t* x1T   = (uint16_t*)alloc((size_t)128*B4*2);
  uint16_t* x2T   = (uint16_t*)alloc((size_t)128*B4*2);
  float*    w2    = (float*)alloc((size_t)B4*512*4);
  (void)ws_size; (void)in_sizes; (void)n_in; (void)out_size;

  hipMemsetAsync(Wbs2T, 0, (size_t)128*KZ*2, stream);

  dim3 blk(256);
  auto tg = [](int nc, int kd){ return dim3((nc+31)/32, kd/32); };
  transpose_pack<<<tg(24576,KZ),blk,0,stream>>>(Ww0, bw0, WpT0, 24576, KZ, 1024, 20992, 192, 164);
  transpose_pack<<<tg(16384,KZ),blk,0,stream>>>(Ww1, bw1, WpT1, 16384, KZ, 1024, 16384, 128, 128);
  transpose_pack<<<tg(512,KZ),blk,0,stream>>>(Ww2, bw2, WpT2, 512, KZ, 1024, 512, 128, 128);
  transpose_pack<<<tg(1024,KH),blk,0,stream>>>(We1, be1, We1T, 1024, KH, 132, 1024, 1024, 1024);
  transpose_pack<<<tg(1024,KZ),blk,0,stream>>>(We2, be2, We2T, 1024, KZ, 1024, 1024, 1024, 1024);
  transpose_pack<<<tg(128,KZ),blk,0,stream>>>(Wb0, bb0, Wbs0T,          128, KZ, 1024, 128, 128, 128);
  transpose_pack<<<tg(128,KZ),blk,0,stream>>>(Ws0, bs0i, Wbs0T + 128*KZ,128, KZ, 1024, 128, 128, 128);
  transpose_pack<<<tg(128,KZ),blk,0,stream>>>(Wb1, bb1, Wbs1T,          128, KZ, 1024, 128, 128, 128);
  transpose_pack<<<tg(128,KZ),blk,0,stream>>>(Ws1, bs1i, Wbs1T + 128*KZ,128, KZ, 1024, 128, 128, 128);
  transpose_pack<<<tg(4,KZ),blk,0,stream>>>(Wb2, bb2, Wbs2T,        4, KZ, 1024, 4, 4, 4);
  transpose_pack<<<tg(4,KZ),blk,0,stream>>>(Ws2, bs2i, Wbs2T + 4*KZ,4, KZ, 1024, 4, 4, 4);

  pack_hin<<<dim3(B4*KH/256),blk,0,stream>>>(obs, prefs, hinp);
  pack_x0T<<<dim3(192*B4/256),blk,0,stream>>>(obs, act, prefs, x0T);
  zinit<<<dim3(B4*128/256),blk,0,stream>>>(z1p, zp);

  // z1 = relu(hin' @ We1')   [B,1024] bf16 into z1p (stride KZ)
  gemm128<1,1,0><<<dim3(32,8),blk,0,stream>>>(hinp, KH, We1T, KH, z1p, KZ, KH);
  // z = relu(z1' @ We2')     [B,1024] bf16 into zp (stride KZ)
  gemm128<1,1,0><<<dim3(32,8),blk,0,stream>>>(z1p, KZ, We2T, KZ, zp, KZ, KZ);
  // bias/scale heads for layers 0+1 in ONE launch: fp32 TRANSPOSED [512][B4]
  gemm128<0,0,1><<<dim3(32,4),blk,0,stream>>>(zp, KZ, Wbs0T, KZ, bsb0, B4, KZ);
  gemm128<0,0,0><<<dim3(32,1),blk,0,stream>>>(zp, KZ, Wbs2T, KZ, bsb2, 128, KZ);

  // fused hyper layers 0 and 1: 1024 blocks (8 xcd * 64 pairs * 2 m-tiles)
  hyper2n<192><<<dim3(1024),dim3(512),0,stream>>>(zp, WpT0, x0T, bsb0, x1T, 1);
  hyper2n<128><<<dim3(1024),dim3(512),0,stream>>>(zp, WpT1, x1T, bsb1, x2T, 1);

  // layer 2: materialize small w2 then finalize
  gemm128<0,0,0><<<dim3(32,4),blk,0,stream>>>(zp, KZ, WpT2, KZ, w2, 512, KZ);
  finalize_k<<<dim3(B4/64),blk,0,stream>>>(w2, x2T, bsb2, (float*)d_out);
}

// Round 9
// 603.235 us; speedup vs baseline: 7.0841x; 1.0392x over previous
//
#include <hip/hip_runtime.h>
#include <hip/hip_bf16.h>
#include <stdint.h>

#define B4 4096
#define KZ 1088   // padded z width: 1024 + 1 (ones col) + 63 pad (34 x 32)
#define KH 160    // padded hypernet-input width: 132 + 1 + pad

typedef short bf16x8 __attribute__((ext_vector_type(8)));
typedef float f32x4 __attribute__((ext_vector_type(4)));

__device__ __forceinline__ float b2f(uint16_t u){
  union {float f; uint32_t i;} v; v.i = ((uint32_t)u)<<16; return v.f;
}
__device__ __forceinline__ uint16_t f2b(float f){
  union {float fv; uint32_t i;} v; v.fv = f;
  uint32_t r = v.i + 0x7FFFu + ((v.i>>16)&1u);
  return (uint16_t)(r>>16);
}
__device__ __forceinline__ void gload16(const void* g, void* l){
  __builtin_amdgcn_global_load_lds(
      (__attribute__((address_space(1))) void*)(g),
      (__attribute__((address_space(3))) void*)(l), 16, 0, 0);
}

// ---------------------------------------------------------------------------
// Transpose+pack: dst[c][k] (bf16, K-contiguous) from src fp32 [Ksrc][src_ld].
// Row k==Ksrc gets bias[sc]; k>Ksrc gets 0. Column map handles din padding:
// o=c/din_dst, i=c%din_dst, valid iff i<din_src. Writes vectorized ushort4.
// ---------------------------------------------------------------------------
__global__ __launch_bounds__(256) void transpose_pack(
    const float* __restrict__ src, const float* __restrict__ bias,
    uint16_t* __restrict__ dst,
    int Ncols, int Kdst, int Ksrc, int src_ld, int din_dst, int din_src)
{
  __shared__ float tile[32][33];
  int ct = blockIdx.x, kt = blockIdx.y;
  int tid = threadIdx.x;
  int cl = tid & 31, kg = tid >> 5;
  #pragma unroll
  for (int r = 0; r < 4; ++r){
    int kl = kg*4 + r;
    int k  = kt*32 + kl;
    int c  = ct*32 + cl;
    float v = 0.f;
    if (c < Ncols){
      int o = c / din_dst, i = c - o*din_dst;
      if (i < din_src){
        int sc = o*din_src + i;
        if (k < Ksrc)       v = src[(size_t)k*src_ld + sc];
        else if (k == Ksrc) v = bias[sc];
      }
    }
    tile[kl][cl] = v;
  }
  __syncthreads();
  int c_loc = tid >> 3, kq = tid & 7;
  int c = ct*32 + c_loc;
  if (c < Ncols){
    ushort4 st;
    uint16_t* sp = (uint16_t*)&st;
    #pragma unroll
    for (int r = 0; r < 4; ++r) sp[r] = f2b(tile[kq*4 + r][c_loc]);
    *(ushort4*)&dst[(size_t)c*Kdst + kt*32 + kq*4] = st;
  }
}

// hinp[b][k] bf16: [obs | prefs | 1 | 0...], width KH
__global__ __launch_bounds__(256) void pack_hin(
    const float* __restrict__ obs, const float* __restrict__ prefs,
    uint16_t* __restrict__ hinp)
{
  int idx = blockIdx.x*256 + threadIdx.x;   // over B4*KH
  int b = idx / KH, k = idx - b*KH;
  float v;
  if (k < 128)      v = obs[b*128 + k];
  else if (k < 132) v = prefs[b*4 + (k-128)];
  else              v = (k == 132) ? 1.f : 0.f;
  hinp[idx] = f2b(v);
}

// x0T[c][b] bf16 transposed: c<128 obs, c<160 action, c<164 prefs, else 0.
__global__ __launch_bounds__(256) void pack_x0T(
    const float* __restrict__ obs, const float* __restrict__ act,
    const float* __restrict__ prefs, uint16_t* __restrict__ x0T)
{
  int idx = blockIdx.x*256 + threadIdx.x;   // over 192*B4
  int c = idx >> 12;
  int b = idx & (B4-1);
  float v = 0.f;
  if (c < 128)      v = obs[b*128 + c];
  else if (c < 160) v = act[b*32 + (c-128)];
  else if (c < 164) v = prefs[b*4 + (c-160)];
  x0T[idx] = f2b(v);
}

// set cols 1024..1087 of z1p and zp: 1.0 at 1024, zeros after
__global__ __launch_bounds__(256) void zinit(uint16_t* __restrict__ z1p,
                                             uint16_t* __restrict__ zp)
{
  int idx = blockIdx.x*256 + threadIdx.x;   // over B4*128
  int t = idx & 127;
  int row = idx >> 7;
  uint16_t* p = (t < 64) ? z1p : zp;
  int col = 1024 + (t & 63);
  p[(size_t)row*KZ + col] = ((t & 63) == 0) ? (uint16_t)0x3F80 : (uint16_t)0;
}

// ---------------------------------------------------------------------------
// Generic 128x128 MFMA GEMM (unchanged).
// ---------------------------------------------------------------------------
template<int RELU, int OUTBF, int TRANS>
__global__ __launch_bounds__(256) void gemm128(
    const uint16_t* __restrict__ A, int lda,
    const uint16_t* __restrict__ BT, int ldb,
    void* __restrict__ Cv, int ldc, int K)
{
  __shared__ char smA[128*64];
  __shared__ char smB[128*64];
  int tid = threadIdx.x, w = tid >> 6, lane = tid & 63;
  int m0 = blockIdx.x*128, n0 = blockIdx.y*128;
  const uint16_t* Ab = A  + (size_t)m0*lda;
  const uint16_t* Bb = BT + (size_t)n0*ldb;
  f32x4 acc[2][8];
  #pragma unroll
  for (int mf = 0; mf < 2; ++mf)
    #pragma unroll
    for (int nf = 0; nf < 8; ++nf) acc[mf][nf] = (f32x4){0.f,0.f,0.f,0.f};
  int colg = lane & 15, hi = lane >> 4;

  for (int k0 = 0; k0 < K; k0 += 32){
    #pragma unroll
    for (int p = 0; p < 2; ++p){
      int rb = p*4 + w;
      int row = rb*16 + (lane >> 2);
      int chunk = (lane & 3) ^ ((row >> 1) & 3);
      gload16(Ab + (size_t)row*lda + k0 + chunk*8, &smA[rb*1024]);
      gload16(Bb + (size_t)row*ldb + k0 + chunk*8, &smB[rb*1024]);
    }
    __syncthreads();
    bf16x8 af[2];
    #pragma unroll
    for (int mf = 0; mf < 2; ++mf){
      int row = w*32 + mf*16 + colg;
      af[mf] = *(const bf16x8*)&smA[row*64 + ((hi ^ ((row>>1)&3)) << 4)];
    }
    #pragma unroll
    for (int nf = 0; nf < 8; ++nf){
      int row = nf*16 + colg;
      bf16x8 bfr = *(const bf16x8*)&smB[row*64 + ((hi ^ ((row>>1)&3)) << 4)];
      acc[0][nf] = __builtin_amdgcn_mfma_f32_16x16x32_bf16(af[0], bfr, acc[0][nf], 0,0,0);
      acc[1][nf] = __builtin_amdgcn_mfma_f32_16x16x32_bf16(af[1], bfr, acc[1][nf], 0,0,0);
    }
    __syncthreads();
  }
  #pragma unroll
  for (int mf = 0; mf < 2; ++mf){
    #pragma unroll
    for (int nf = 0; nf < 8; ++nf){
      int col = n0 + nf*16 + colg;
      #pragma unroll
      for (int r = 0; r < 4; ++r){
        int row = m0 + w*32 + mf*16 + hi*4 + r;
        float v = acc[mf][nf][r];
        if (RELU) v = v > 0.f ? v : 0.f;
        if (TRANS)      ((float*)Cv)[(size_t)col*ldc + row] = v;
        else if (OUTBF) ((uint16_t*)Cv)[(size_t)row*ldc + col] = f2b(v);
        else            ((float*)Cv)[(size_t)row*ldc + col] = v;
      }
    }
  }
}

// ---------------------------------------------------------------------------
// Fused hypernet layer v9: r8 geometry (256 samples x 2 neurons, 8 waves
// 2M x 4N, 3 LDS half-buffers, counted vmcnt, 1 barrier/half) but the
// compute section is COMPILER-SCHEDULED: no lgkmcnt(0)/sched_barrier pinning
// (rule: order-pinning defeats the compiler's counted-lgkm interleave).
// Epilogue reduces per-mf into LDS (4 live floats) to kill the pp[8][4]
// scratch spill (r6/r8's 63MB WRITE_SIZE).
// Hazard audit: every frag read is consumed by an MFMA before the wave
// reaches the next barrier; staging into that buffer is issued only after
// that barrier -> no drain needed.
// ---------------------------------------------------------------------------
template<int DINP>
__global__ __launch_bounds__(512, 2) void hyper2n(
    const uint16_t* __restrict__ zp,     // [B4, KZ]
    const uint16_t* __restrict__ WpT,    // [128*DINP, KZ] grouped by neuron
    const uint16_t* __restrict__ xT,     // [DINP, B4]
    const float*  __restrict__ bsbT,     // [256, B4]: row o=bias, 128+o=scale
    uint16_t* __restrict__ outT,         // [128, B4]
    int relu)
{
  constexpr int NF     = DINP/32;        // frags per wave per k-half (6 / 4)
  constexpr int BCALLS = DINP/64;        // B stage calls per half (3 / 2)
  constexpr int WAITN  = 2 + BCALLS;     // counted vmcnt at half boundary
  constexpr int HBUF   = 16384 + 2*DINP*64;  // A 16KB + B 2*DINP rows x 64B
  constexpr int NH     = KZ/32;          // 34 half-tiles
  __shared__ char sm[3*HBUF];

  int tid = threadIdx.x, w = tid >> 6, lane = tid & 63;
  int wm = w >> 2, wn = w & 3;           // 2M x 4N
  // XCD decode: 1024 blocks; each XCD owns 2 m-tiles x all 64 neuron-pairs
  int f = blockIdx.x;
  int xcd = f & 7;
  int j = f >> 3;               // 0..127
  int pair = j >> 1;            // 0..63
  int mt = xcd*2 + (j & 1);     // 0..15
  int m0 = mt*256;
  const uint16_t* Ag = zp  + (size_t)m0*KZ;
  const uint16_t* Bg = WpT + (size_t)pair*(2*DINP)*KZ;
  int colg = lane & 15, hi = lane >> 4;

  f32x4 acc[8][NF];
  #pragma unroll
  for (int mf = 0; mf < 8; ++mf)
    #pragma unroll
    for (int nf = 0; nf < NF; ++nf) acc[mf][nf] = (f32x4){0.f,0.f,0.f,0.f};

  // stage call: 512 threads x 16B = 8KB = 128 rows x 64B. Linear LDS dest
  // (wave-uniform base + lane*16); 16B-chunk pre-swizzled by (row>>1)&3.
  auto SA = [&](int h, int a){
    int row = a*128 + (tid >> 2);
    int ch  = (tid & 3) ^ ((row >> 1) & 3);
    gload16(Ag + (size_t)row*KZ + h*32 + ch*8,
            sm + (h%3)*HBUF + a*8192 + w*1024);
  };
  auto SB = [&](int h, int b){
    int row = b*128 + (tid >> 2);
    int ch  = (tid & 3) ^ ((row >> 1) & 3);
    gload16(Bg + (size_t)row*KZ + h*32 + ch*8,
            sm + (h%3)*HBUF + 16384 + b*8192 + w*1024);
  };

  // prologue: stage halves 0 and 1
  SA(0,0); SA(0,1);
  #pragma unroll
  for (int b = 0; b < BCALLS; ++b) SB(0,b);
  SA(1,0); SA(1,1);
  #pragma unroll
  for (int b = 0; b < BCALLS; ++b) SB(1,b);

  for (int h = 0; h < NH; ++h){
    const char* base = sm + (h%3)*HBUF;
    if (h == NH-1) asm volatile("s_waitcnt vmcnt(0)" ::: "memory");
    else           asm volatile("s_waitcnt vmcnt(%0)" :: "i"(WAITN) : "memory");
    __builtin_amdgcn_s_barrier();
    // issue next-next staging (into the buffer read at h-1; safe post-barrier)
    if (h + 2 < NH){
      SA(h+2,0); SA(h+2,1);
      #pragma unroll
      for (int b = 0; b < BCALLS; ++b) SB(h+2,b);
    }
    // compute: plain loads + MFMAs, compiler emits counted lgkm interleave
    bf16x8 Bf[NF];
    #pragma unroll
    for (int nf = 0; nf < NF; ++nf){
      int rc = wn*(DINP/2) + nf*16 + colg;
      Bf[nf] = *(const bf16x8*)(base + 16384 + rc*64 + ((hi ^ ((rc>>1)&3)) << 4));
    }
    #pragma unroll
    for (int m = 0; m < 8; ++m){
      int row = wm*128 + m*16 + colg;
      bf16x8 a = *(const bf16x8*)(base + row*64 + ((hi ^ ((row>>1)&3)) << 4));
      #pragma unroll
      for (int nf = 0; nf < NF; ++nf)
        acc[m][nf] = __builtin_amdgcn_mfma_f32_16x16x32_bf16(a, Bf[nf], acc[m][nf], 0,0,0);
    }
  }

  // ---- epilogue: per-mf contract + reduce + LDS store (no pp array) ----
  __syncthreads();
  float* red = (float*)sm;    // [2 parity][2 o_loc][256]
  int parity = wn & 1, o_loc = wn >> 1;
  #pragma unroll
  for (int mf = 0; mf < 8; ++mf){
    float p0=0.f, p1=0.f, p2=0.f, p3=0.f;
    int b0 = m0 + wm*128 + mf*16 + hi*4;
    #pragma unroll
    for (int nf = 0; nf < NF; ++nf){
      int il = parity*(DINP/2) + nf*16 + colg;
      ushort4 xv = *(const ushort4*)(xT + (size_t)il*B4 + b0);
      f32x4 a = acc[mf][nf];
      p0 += a[0]*b2f(xv.x); p1 += a[1]*b2f(xv.y);
      p2 += a[2]*b2f(xv.z); p3 += a[3]*b2f(xv.w);
    }
    #pragma unroll
    for (int off = 1; off < 16; off <<= 1){
      p0 += __shfl_xor(p0, off); p1 += __shfl_xor(p1, off);
      p2 += __shfl_xor(p2, off); p3 += __shfl_xor(p3, off);
    }
    if (colg == 0){
      int rloc = wm*128 + mf*16 + hi*4;
      float* rp = red + parity*512 + o_loc*256 + rloc;
      rp[0] = p0; rp[1] = p1; rp[2] = p2; rp[3] = p3;
    }
  }
  __syncthreads();
  // final combine: one thread per (o_loc, row); coalesced loads and stores
  {
    int o_l = tid >> 8, row = tid & 255;
    int o = pair*2 + o_l;
    float v = red[o_l*256 + row] + red[512 + o_l*256 + row];
    float bv = bsbT[(size_t)o*B4 + m0 + row];
    float sv = bsbT[(size_t)(128+o)*B4 + m0 + row];
    float val = (v + bv) * sv;
    if (relu) val = val > 0.f ? val : 0.f;
    outT[(size_t)o*B4 + m0 + row] = f2b(val);
  }
}

// final layer: out[b,o] = (sum_i w2[b,o*128+i]*x2[i,b] + b2[b,o]) * s2[b,o]
__global__ __launch_bounds__(256) void finalize_k(
    const float* __restrict__ w2, const uint16_t* __restrict__ x2T,
    const float* __restrict__ bs2, float* __restrict__ out)
{
  int tid = threadIdx.x;
  int o = tid & 3;
  int b = blockIdx.x*64 + (tid >> 2);
  const float* wr = w2 + (size_t)b*512 + o*128;
  float dot = 0.f;
  #pragma unroll
  for (int i = 0; i < 128; i += 4){
    float4 wv = *(const float4*)(wr + i);
    dot += wv.x * b2f(x2T[(size_t)(i+0)*B4 + b]);
    dot += wv.y * b2f(x2T[(size_t)(i+1)*B4 + b]);
    dot += wv.z * b2f(x2T[(size_t)(i+2)*B4 + b]);
    dot += wv.w * b2f(x2T[(size_t)(i+3)*B4 + b]);
  }
  float bv = bs2[(size_t)b*128 + o];
  float sv = bs2[(size_t)b*128 + 4 + o];
  out[b*4 + o] = (dot + bv) * sv;
}

// ---------------------------------------------------------------------------
extern "C" void kernel_launch(void* const* d_in, const int* in_sizes, int n_in,
                              void* d_out, int out_size, void* d_ws, size_t ws_size,
                              hipStream_t stream)
{
  const float* obs   = (const float*)d_in[0];
  const float* act   = (const float*)d_in[1];
  const float* prefs = (const float*)d_in[2];
  const float* We1 = (const float*)d_in[3];
  const float* be1 = (const float*)d_in[4];
  const float* We2 = (const float*)d_in[5];
  const float* be2 = (const float*)d_in[6];
  const float* Ww0 = (const float*)d_in[7],  *bw0 = (const float*)d_in[8];
  const float* Wb0 = (const float*)d_in[9],  *bb0 = (const float*)d_in[10];
  const float* Ws0 = (const float*)d_in[11], *bs0i = (const float*)d_in[12];
  const float* Ww1 = (const float*)d_in[13], *bw1 = (const float*)d_in[14];
  const float* Wb1 = (const float*)d_in[15], *bb1 = (const float*)d_in[16];
  const float* Ws1 = (const float*)d_in[17], *bs1i = (const float*)d_in[18];
  const float* Ww2 = (const float*)d_in[19], *bw2 = (const float*)d_in[20];
  const float* Wb2 = (const float*)d_in[21], *bb2 = (const float*)d_in[22];
  const float* Ws2 = (const float*)d_in[23], *bs2i = (const float*)d_in[24];

  char* ws = (char*)d_ws;
  size_t off = 0;
  auto alloc = [&](size_t bytes)->char*{
    char* p = ws + off; off += (bytes + 255) & ~(size_t)255; return p;
  };
  uint16_t* WpT0  = (uint16_t*)alloc((size_t)24576*KZ*2);  // 128 * 192 rows
  uint16_t* WpT1  = (uint16_t*)alloc((size_t)16384*KZ*2);
  uint16_t* WpT2  = (uint16_t*)alloc((size_t)512*KZ*2);
  uint16_t* We1T  = (uint16_t*)alloc((size_t)1024*KH*2);
  uint16_t* We2T  = (uint16_t*)alloc((size_t)1024*KZ*2);
  uint16_t* Wbs0T = (uint16_t*)alloc((size_t)256*KZ*2);    // contiguous with
  uint16_t* Wbs1T = (uint16_t*)alloc((size_t)256*KZ*2);    // Wbs0T (512 rows)
  uint16_t* Wbs2T = (uint16_t*)alloc((size_t)128*KZ*2);
  uint16_t* hinp  = (uint16_t*)alloc((size_t)B4*KH*2);
  uint16_t* z1p   = (uint16_t*)alloc((size_t)B4*KZ*2);
  uint16_t* zp    = (uint16_t*)alloc((size_t)B4*KZ*2);
  float*    bsb0  = (float*)alloc((size_t)256*B4*4);   // transposed [256][B4]
  float*    bsb1  = (float*)alloc((size_t)256*B4*4);   // contiguous with bsb0
  float*    bsb2  = (float*)alloc((size_t)B4*128*4);
  uint16_t* x0T   = (uint16_t*)alloc((size_t)192*B4*2);
  uint16_t* x1T   = (uint16_t*)alloc((size_t)128*B4*2);
  uint16_t* x2T   = (uint16_t*)alloc((size_t)128*B4*2);
  float*    w2    = (float*)alloc((size_t)B4*512*4);
  (void)ws_size; (void)in_sizes; (void)n_in; (void)out_size;

  hipMemsetAsync(Wbs2T, 0, (size_t)128*KZ*2, stream);

  dim3 blk(256);
  auto tg = [](int nc, int kd){ return dim3((nc+31)/32, kd/32); };
  transpose_pack<<<tg(24576,KZ),blk,0,stream>>>(Ww0, bw0, WpT0, 24576, KZ, 1024, 20992, 192, 164);
  transpose_pack<<<tg(16384,KZ),blk,0,stream>>>(Ww1, bw1, WpT1, 16384, KZ, 1024, 16384, 128, 128);
  transpose_pack<<<tg(512,KZ),blk,0,stream>>>(Ww2, bw2, WpT2, 512, KZ, 1024, 512, 128, 128);
  transpose_pack<<<tg(1024,KH),blk,0,stream>>>(We1, be1, We1T, 1024, KH, 132, 1024, 1024, 1024);
  transpose_pack<<<tg(1024,KZ),blk,0,stream>>>(We2, be2, We2T, 1024, KZ, 1024, 1024, 1024, 1024);
  transpose_pack<<<tg(128,KZ),blk,0,stream>>>(Wb0, bb0, Wbs0T,          128, KZ, 1024, 128, 128, 128);
  transpose_pack<<<tg(128,KZ),blk,0,stream>>>(Ws0, bs0i, Wbs0T + 128*KZ,128, KZ, 1024, 128, 128, 128);
  transpose_pack<<<tg(128,KZ),blk,0,stream>>>(Wb1, bb1, Wbs1T,          128, KZ, 1024, 128, 128, 128);
  transpose_pack<<<tg(128,KZ),blk,0,stream>>>(Ws1, bs1i, Wbs1T + 128*KZ,128, KZ, 1024, 128, 128, 128);
  transpose_pack<<<tg(4,KZ),blk,0,stream>>>(Wb2, bb2, Wbs2T,        4, KZ, 1024, 4, 4, 4);
  transpose_pack<<<tg(4,KZ),blk,0,stream>>>(Ws2, bs2i, Wbs2T + 4*KZ,4, KZ, 1024, 4, 4, 4);

  pack_hin<<<dim3(B4*KH/256),blk,0,stream>>>(obs, prefs, hinp);
  pack_x0T<<<dim3(192*B4/256),blk,0,stream>>>(obs, act, prefs, x0T);
  zinit<<<dim3(B4*128/256),blk,0,stream>>>(z1p, zp);

  // z1 = relu(hin' @ We1')   [B,1024] bf16 into z1p (stride KZ)
  gemm128<1,1,0><<<dim3(32,8),blk,0,stream>>>(hinp, KH, We1T, KH, z1p, KZ, KH);
  // z = relu(z1' @ We2')     [B,1024] bf16 into zp (stride KZ)
  gemm128<1,1,0><<<dim3(32,8),blk,0,stream>>>(z1p, KZ, We2T, KZ, zp, KZ, KZ);
  // bias/scale heads for layers 0+1 in ONE launch: fp32 TRANSPOSED [512][B4]
  gemm128<0,0,1><<<dim3(32,4),blk,0,stream>>>(zp, KZ, Wbs0T, KZ, bsb0, B4, KZ);
  gemm128<0,0,0><<<dim3(32,1),blk,0,stream>>>(zp, KZ, Wbs2T, KZ, bsb2, 128, KZ);

  // fused hyper layers 0 and 1: 1024 blocks (8 xcd * 64 pairs * 2 m-tiles)
  hyper2n<192><<<dim3(1024),dim3(512),0,stream>>>(zp, WpT0, x0T, bsb0, x1T, 1);
  hyper2n<128><<<dim3(1024),dim3(512),0,stream>>>(zp, WpT1, x1T, bsb1, x2T, 1);

  // layer 2: materialize small w2 then finalize
  gemm128<0,0,0><<<dim3(32,4),blk,0,stream>>>(zp, KZ, WpT2, KZ, w2, 512, KZ);
  finalize_k<<<dim3(B4/64),blk,0,stream>>>(w2, x2T, bsb2, (float*)d_out);
}